// Round 5
// baseline (397.053 us; speedup 1.0000x reference)
//
#include <hip/hip_runtime.h>
#include <stdint.h>

// Problem dims
#define BB   64
#define TSEQ 128
#define ISEQ 197
#define DD   768
#define TM   127   // text tokens used (drop token 0)
#define IM   196   // image tokens used (drop token 0)
#define NK   24    // 768 / 32
#define A_KB (TM*64)   // bytes per K-step block of one text matrix
#define B_KB (IM*64)   // bytes per K-step block of one image matrix

// LDS map (bytes): B tbuf 3x14336 | rowKeys 512 | colKeys 896 | parts 64
#define LDS_RK   43008
#define LDS_CK   43520
#define LDS_PT   44416
#define LDS_TOT  44480

typedef float    f32x4 __attribute__((ext_vector_type(4)));
typedef _Float16 h8    __attribute__((ext_vector_type(8)));
typedef _Float16 h4    __attribute__((ext_vector_type(4)));
typedef float    fvec4 __attribute__((ext_vector_type(4)));

__device__ __forceinline__ unsigned fkey(float f){
  unsigned u = __float_as_uint(f);
  return (u & 0x80000000u) ? ~u : (u | 0x80000000u);
}
__device__ __forceinline__ float fdekey(unsigned k){
  unsigned u = (k & 0x80000000u) ? (k & 0x7fffffffu) : ~k;
  return __uint_as_float(u);
}
__device__ __forceinline__ float waveSum(float v){
  #pragma unroll
  for (int s = 1; s < 64; s <<= 1) v += __shfl_xor(v, s, 64);
  return v;
}

__device__ __forceinline__ void gload_lds16(const void* g, void* l){
  __builtin_amdgcn_global_load_lds(
      (const __attribute__((address_space(1))) void*)g,
      (__attribute__((address_space(3))) void*)l, 16, 0, 0);
}

// ---------------------------------------------------------------------------
__global__ void mask_kernel(const int* __restrict__ pmG, float* __restrict__ bias,
                            float* __restrict__ sel, int* __restrict__ cnt)
{
  int b = blockIdx.x; int l = threadIdx.x;          // 64 threads
  const int* row = pmG + b*TSEQ;
  int p0 = row[l]; int p1 = row[l+64];
  unsigned long long m0 = __ballot(p0 == 0);
  unsigned long long m1 = __ballot(p1 == 0);
  int lz = 0;
  if (m1)      lz = 64 + (63 - __clzll(m1));
  else if (m0) lz = 63 - __clzll(m0);
  int t1 = l + 1;
  int q1 = row[t1];
  bool v1 = (q1 == 0) && (t1 != lz);
  int t2 = l + 65;
  bool v2 = false;
  if (t2 < TSEQ){ int q2 = row[t2]; v2 = (q2 == 0) && (t2 != lz); }
  bias[b*128 + l]      = v1 ? 0.f : -3.0e38f;
  sel [b*128 + l]      = v1 ? 1.f : 0.f;
  bias[b*128 + 64 + l] = v2 ? 0.f : -3.0e38f;
  sel [b*128 + 64 + l] = v2 ? 1.f : 0.f;
  unsigned long long vm1 = __ballot(v1);
  unsigned long long vm2 = __ballot(v2);
  if (l == 0) cnt[b] = __popcll(vm1) + __popcll(vm2);
}

// ---------------------------------------------------------------------------
// f32 -> fp16 conversion into K-blocked layout: [b][ks][token][32 halves]
__global__ void cvt_txt_kernel(const float* __restrict__ src, _Float16* __restrict__ dst){
  int t = blockIdx.x;   // 0..126
  int b = blockIdx.y;
  int i = threadIdx.x;  // 0..191
  const fvec4* s = (const fvec4*)(src + ((size_t)b*TSEQ + t + 1)*DD) + i;
  fvec4 v = *s;
  h4 h; h.x=(_Float16)v.x; h.y=(_Float16)v.y; h.z=(_Float16)v.z; h.w=(_Float16)v.w;
  int ks = i >> 3; int o = (i & 7)*4;
  _Float16* d = dst + (size_t)b*(NK*TM*32) + (size_t)ks*(TM*32) + t*32 + o;
  *(h4*)d = h;
}
__global__ void cvt_img_kernel(const float* __restrict__ src, _Float16* __restrict__ dst){
  int t = blockIdx.x;   // 0..195
  int b = blockIdx.y;
  int i = threadIdx.x;
  const fvec4* s = (const fvec4*)(src + ((size_t)b*ISEQ + t + 1)*DD) + i;
  fvec4 v = *s;
  h4 h; h.x=(_Float16)v.x; h.y=(_Float16)v.y; h.z=(_Float16)v.z; h.w=(_Float16)v.w;
  int ks = i >> 3; int o = (i & 7)*4;
  _Float16* d = dst + (size_t)b*(NK*IM*32) + (size_t)ks*(IM*32) + t*32 + o;
  *(h4*)d = h;
}

// ---------------------------------------------------------------------------
// Main: one workgroup per (bx=text, by=image) pair. 128x224x768 f16 MFMA.
// A-frags global->VGPR direct (prefetch depth 1, L2-resident); B staged via
// global_load_lds into triple-buffered swizzled LDS (prefetch depth 2).
// ONE barrier per K-step + one counted vmcnt(8) — loads never drain to 0.
// __launch_bounds__(256,3): 3 blocks/CU target (the occupancy lever).
__global__ __launch_bounds__(256, 3)
void cmli_pair_kernel(const _Float16* __restrict__ txtH,
                      const _Float16* __restrict__ imgH,
                      const float* __restrict__ biasG,
                      const float* __restrict__ selG,
                      const int* __restrict__ cntG,
                      const float* __restrict__ scaleP,
                      float* __restrict__ out)
{
  __shared__ __align__(16) char smem[LDS_TOT];
  unsigned* rowKeys = (unsigned*)(smem + LDS_RK);
  unsigned* colKeys = (unsigned*)(smem + LDS_CK);
  float*    parts   = (float*)(smem + LDS_PT);

  const int tid  = threadIdx.x;
  const int lane = tid & 63;
  const int w    = tid >> 6;
  const int wm   = w & 1;      // M interleave class
  const int wn   = w >> 1;     // N half (0..1)
  const int bx   = blockIdx.x >> 6;   // text index
  const int by   = blockIdx.x & 63;   // image index

  const char* tA = (const char*)txtH + (size_t)bx * (NK*A_KB);
  const char* tB = (const char*)imgH + (size_t)by * (NK*B_KB);
  const int mtc = (cntG[bx] + 15) >> 4;   // active m-tiles, 4..8

  // B staging table (source pre-swizzled so linear LDS dest = swizzled layout)
  // 14 chunks of 1024B; uniform 4 per wave (chunk 13 staged twice — benign).
  int bSrc[4], bLds[4];
  #pragma unroll
  for (int i=0;i<4;i++){
    int c = w + 4*i; if (c > 13) c = 13;
    int p = c*64 + lane; int r = p>>2; int pg = p&3;
    int g = pg ^ ((r>>1)&3);
    bSrc[i] = min(r,195)*64 + g*16; bLds[i] = c*1024;
  }

  // B fragment read offset (swizzle-consistent)
  const int pgf  = (lane>>4) ^ ((lane>>1)&3);
  const int bOff = (wn*112 + (lane&15))*64 + pgf*16;   // + n*1024 + buf base

  // A fragment global offsets (direct MFMA layout: row*64 + (lane>>4)*16)
  int aG[4];
  #pragma unroll
  for (int j=0;j<4;j++){
    int row = (wm + 2*j)*16 + (lane&15);
    aG[j] = min(row,126)*64 + (lane>>4)*16;
  }

  f32x4 acc[4][7];
  #pragma unroll
  for (int j=0;j<4;j++)
    #pragma unroll
    for (int n=0;n<7;n++)
      acc[j][n] = (f32x4){0.f,0.f,0.f,0.f};

  if (tid < 128) rowKeys[tid] = 0u;
  if (tid < 224) colKeys[tid] = 0u;

  h8 af_cur[4], af_nxt[4];

  // prologue: stage B(0)->buf0, B(1)->buf1; load af(0).
  // vmcnt(8) drains B(0), leaves B(1)(4)+af(0)(4) in flight.
  {
    #pragma unroll
    for (int i=0;i<4;i++) gload_lds16(tB + bSrc[i], smem + bLds[i]);
    const char* b1 = tB + B_KB;
    #pragma unroll
    for (int i=0;i<4;i++) gload_lds16(b1 + bSrc[i], smem + 14336 + bLds[i]);
    #pragma unroll
    for (int j=0;j<4;j++) af_cur[j] = *(const h8*)(tA + aG[j]);
    asm volatile("s_waitcnt vmcnt(8)" ::: "memory");
    __builtin_amdgcn_s_barrier();
  }

  const char* aPtr = tA + A_KB;            // af(t+1) source
  const char* bPtr = tB + 2*(size_t)B_KB;  // B(t+2) source
  int rbB = 0;
  for (int t=0; t<NK; t++){
    const char* Bb = smem + rbB*14336;
    int sb = rbB + 2; if (sb >= 3) sb -= 3;
    char* Sb = smem + sb*14336;

    // issue B(t+2) DMA first, then af(t+1) prefetch
    #pragma unroll
    for (int i=0;i<4;i++) gload_lds16(bPtr + bSrc[i], Sb + bLds[i]);
    #pragma unroll
    for (int j=0;j<4;j++) af_nxt[j] = *(const h8*)(aPtr + aG[j]);

    // compute: stream B frags (one live bf), MFMA into acc
    #pragma unroll
    for (int n=0;n<7;n++){
      h8 bf = *(const h8*)(Bb + bOff + n*1024);
      #pragma unroll
      for (int j=0;j<4;j++){
        int g = wm + 2*j;
        if (g < mtc)
          acc[j][n] = __builtin_amdgcn_mfma_f32_16x16x32_f16(af_cur[j], bf, acc[j][n], 0,0,0);
      }
    }

    // counted wait: drains B(t+1); B(t+2)+af(t+1) stay in flight
    asm volatile("s_waitcnt vmcnt(8)" ::: "memory");
    __builtin_amdgcn_s_barrier();

    #pragma unroll
    for (int j=0;j<4;j++) af_cur[j] = af_nxt[j];
    aPtr += A_KB; bPtr += B_KB;
    rbB++; if (rbB >= 3) rbB = 0;
  }

  // --- fused reductions ---
  const float scale = scaleP[0];
  #pragma unroll
  for (int j=0;j<4;j++){
    int g = wm + 2*j;
    if (g < mtc){
      #pragma unroll
      for (int n=0;n<7;n++) acc[j][n] *= scale;
    }
  }

  // rowmax (t2i); C/D map: row=(lane>>4)*4+q, col=lane&15
  #pragma unroll
  for (int j=0;j<4;j++){
    int g = wm + 2*j;
    if (g < mtc){
      f32x4 r = acc[j][0];
      #pragma unroll
      for (int n=1;n<7;n++){
        r.x = fmaxf(r.x, acc[j][n].x); r.y = fmaxf(r.y, acc[j][n].y);
        r.z = fmaxf(r.z, acc[j][n].z); r.w = fmaxf(r.w, acc[j][n].w);
      }
      #pragma unroll
      for (int s=1;s<16;s<<=1){
        r.x = fmaxf(r.x, __shfl_xor(r.x, s, 64));
        r.y = fmaxf(r.y, __shfl_xor(r.y, s, 64));
        r.z = fmaxf(r.z, __shfl_xor(r.z, s, 64));
        r.w = fmaxf(r.w, __shfl_xor(r.w, s, 64));
      }
      if ((lane & 15) == 0){
        int row = g*16 + (lane>>4)*4;
        atomicMax(&rowKeys[row+0], fkey(r.x));
        atomicMax(&rowKeys[row+1], fkey(r.y));
        atomicMax(&rowKeys[row+2], fkey(r.z));
        atomicMax(&rowKeys[row+3], fkey(r.w));
      }
    }
  }

  // colmax (i2t): max over valid rows (bias = 0 valid / -3e38 masked)
  #pragma unroll
  for (int n=0;n<7;n++){
    float c = -3.0e38f;
    #pragma unroll
    for (int j=0;j<4;j++){
      int g = wm + 2*j;
      if (g < mtc){
        fvec4 bv = *(const fvec4*)(biasG + bx*128 + g*16 + (lane>>4)*4);
        c = fmaxf(c, acc[j][n].x + bv.x);
        c = fmaxf(c, acc[j][n].y + bv.y);
        c = fmaxf(c, acc[j][n].z + bv.z);
        c = fmaxf(c, acc[j][n].w + bv.w);
      }
    }
    c = fmaxf(c, __shfl_xor(c, 16, 64));
    c = fmaxf(c, __shfl_xor(c, 32, 64));
    if (lane < 16){
      int col = wn*112 + n*16 + lane;
      atomicMax(&colKeys[col], fkey(c));
    }
  }
  __syncthreads();

  // finalize pair outputs
  float v = 0.f;
  if (tid < 128){
    float s = selG[bx*128 + tid];
    v = (s > 0.5f) ? fdekey(rowKeys[tid]) : 0.f;
  }
  float u = (tid < IM) ? fdekey(colKeys[tid]) : 0.f;
  v = waveSum(v); u = waveSum(u);
  if (lane == 0){ parts[w] = v; parts[4+w] = u; }
  __syncthreads();
  if (tid == 0){
    float numer = parts[0]+parts[1]+parts[2]+parts[3];
    float csum  = parts[4]+parts[5]+parts[6]+parts[7];
    float denom = fmaxf((float)cntG[bx], 1e-6f);
    out[1 + 4096 + blockIdx.x] = numer / denom;        // t2i[x][y]
    out[1 + blockIdx.x]        = csum * (1.f/196.f);   // i2t[x][y]
  }
}

// ---------------------------------------------------------------------------
__global__ void loss_kernel(float* __restrict__ out){
  __shared__ float p[2];
  int w = threadIdx.x >> 6, lane = threadIdx.x & 63;
  const float* M = out + 1 + w*4096;
  const float* r = M + lane*64;
  float mx = -3.0e38f;
  for (int j=0;j<64;j++) mx = fmaxf(mx, r[j]);
  float se = 0.f;
  for (int j=0;j<64;j++) se += __expf(r[j]-mx);
  float nll = (mx + __logf(se)) - r[lane];
  float s = waveSum(nll);
  if (lane == 0) p[w] = s;
  __syncthreads();
  if (threadIdx.x == 0) out[0] = (p[0] + p[1]) * (0.5f/64.f);
}

// ---------------------------------------------------------------------------
extern "C" void kernel_launch(void* const* d_in, const int* in_sizes, int n_in,
                              void* d_out, int out_size, void* d_ws, size_t ws_size,
                              hipStream_t stream)
{
  const float* imgF   = (const float*)d_in[0];  // (64,197,768) f32
  const float* txtF   = (const float*)d_in[1];  // (64,128,768) f32
  const int*   pm     = (const int*)d_in[2];    // (64,128) i32
  const float* scaleP = (const float*)d_in[3];  // (1,) f32
  float* out = (float*)d_out;                   // [loss(1) | i2t(4096) | t2i(4096)]

  char* ws = (char*)d_ws;
  _Float16* txtH = (_Float16*)ws;                        // 12,484,608 B
  _Float16* imgH = (_Float16*)(ws + 12484608);           // 19,267,584 B
  float* bias = (float*)(ws + 31752192);                 // 32 KB
  float* sel  = (float*)(ws + 31784960);                 // 32 KB
  int*   cnt  = (int*)(ws + 31817728);                   // 256 B

  hipLaunchKernelGGL(mask_kernel,    dim3(BB),      dim3(64),  0, stream, pm, bias, sel, cnt);
  hipLaunchKernelGGL(cvt_txt_kernel, dim3(TM, BB),  dim3(192), 0, stream, txtF, txtH);
  hipLaunchKernelGGL(cvt_img_kernel, dim3(IM, BB),  dim3(192), 0, stream, imgF, imgH);
  hipLaunchKernelGGL(cmli_pair_kernel, dim3(BB*BB), dim3(256), 0, stream,
                     txtH, imgH, bias, sel, cnt, scaleP, out);
  hipLaunchKernelGGL(loss_kernel,    dim3(1),       dim3(128), 0, stream, out);
}

// Round 6
// 228.072 us; speedup vs baseline: 1.7409x; 1.7409x over previous
//
#include <hip/hip_runtime.h>
#include <stdint.h>

// Problem dims
#define BB   64
#define TSEQ 128
#define ISEQ 197
#define DD   768
#define TM   127   // text tokens used (drop token 0)
#define IM   196   // image tokens used (drop token 0)
#define NK   24    // 768 / 32 (K=32 granules in the converted layout)
#define NK2  12    // BK=64 iterations
#define A_KB (TM*64)   // bytes per K=32 block of one text matrix
#define B_KB (IM*64)   // bytes per K=32 block of one image matrix

// Dynamic LDS map (bytes):
// A slots [cur][kh] 4 x 16384 | B slots [cur][kh] 4 x 14336 | rowKeys 1KB | colKeys 2KB | parts 64B
#define LDS_RK   122880
#define LDS_CK   123904
#define LDS_PT   125952
#define LDS_TOT  126016

typedef float    f32x4 __attribute__((ext_vector_type(4)));
typedef _Float16 h8    __attribute__((ext_vector_type(8)));
typedef _Float16 h4    __attribute__((ext_vector_type(4)));
typedef float    fvec4 __attribute__((ext_vector_type(4)));

__device__ __forceinline__ unsigned fkey(float f){
  unsigned u = __float_as_uint(f);
  return (u & 0x80000000u) ? ~u : (u | 0x80000000u);
}
__device__ __forceinline__ float fdekey(unsigned k){
  unsigned u = (k & 0x80000000u) ? (k & 0x7fffffffu) : ~k;
  return __uint_as_float(u);
}
__device__ __forceinline__ float waveSum(float v){
  #pragma unroll
  for (int s = 1; s < 64; s <<= 1) v += __shfl_xor(v, s, 64);
  return v;
}

__device__ __forceinline__ void gload_lds16(const void* g, void* l){
  __builtin_amdgcn_global_load_lds(
      (const __attribute__((address_space(1))) void*)g,
      (__attribute__((address_space(3))) void*)l, 16, 0, 0);
}

// ---------------------------------------------------------------------------
__global__ void mask_kernel(const int* __restrict__ pmG, float* __restrict__ bias,
                            float* __restrict__ sel, int* __restrict__ cnt)
{
  int b = blockIdx.x; int l = threadIdx.x;          // 64 threads
  const int* row = pmG + b*TSEQ;
  int p0 = row[l]; int p1 = row[l+64];
  unsigned long long m0 = __ballot(p0 == 0);
  unsigned long long m1 = __ballot(p1 == 0);
  int lz = 0;
  if (m1)      lz = 64 + (63 - __clzll(m1));
  else if (m0) lz = 63 - __clzll(m0);
  int t1 = l + 1;
  int q1 = row[t1];
  bool v1 = (q1 == 0) && (t1 != lz);
  int t2 = l + 65;
  bool v2 = false;
  if (t2 < TSEQ){ int q2 = row[t2]; v2 = (q2 == 0) && (t2 != lz); }
  bias[b*128 + l]      = v1 ? 0.f : -3.0e38f;
  sel [b*128 + l]      = v1 ? 1.f : 0.f;
  bias[b*128 + 64 + l] = v2 ? 0.f : -3.0e38f;
  sel [b*128 + 64 + l] = v2 ? 1.f : 0.f;
  unsigned long long vm1 = __ballot(v1);
  unsigned long long vm2 = __ballot(v2);
  if (l == 0) cnt[b] = __popcll(vm1) + __popcll(vm2);
}

// ---------------------------------------------------------------------------
// f32 -> fp16 conversion into K-blocked layout: [b][ks][token][32 halves]
__global__ void cvt_txt_kernel(const float* __restrict__ src, _Float16* __restrict__ dst){
  int t = blockIdx.x;   // 0..126
  int b = blockIdx.y;
  int i = threadIdx.x;  // 0..191
  const fvec4* s = (const fvec4*)(src + ((size_t)b*TSEQ + t + 1)*DD) + i;
  fvec4 v = *s;
  h4 h; h.x=(_Float16)v.x; h.y=(_Float16)v.y; h.z=(_Float16)v.z; h.w=(_Float16)v.w;
  int ks = i >> 3; int o = (i & 7)*4;
  _Float16* d = dst + (size_t)b*(NK*TM*32) + (size_t)ks*(TM*32) + t*32 + o;
  *(h4*)d = h;
}
__global__ void cvt_img_kernel(const float* __restrict__ src, _Float16* __restrict__ dst){
  int t = blockIdx.x;   // 0..195
  int b = blockIdx.y;
  int i = threadIdx.x;
  const fvec4* s = (const fvec4*)(src + ((size_t)b*ISEQ + t + 1)*DD) + i;
  fvec4 v = *s;
  h4 h; h.x=(_Float16)v.x; h.y=(_Float16)v.y; h.z=(_Float16)v.z; h.w=(_Float16)v.w;
  int ks = i >> 3; int o = (i & 7)*4;
  _Float16* d = dst + (size_t)b*(NK*IM*32) + (size_t)ks*(IM*32) + t*32 + o;
  *(h4*)d = h;
}

// ---------------------------------------------------------------------------
// 8-phase-template port: one workgroup per (text-pair bxp, image by).
// 512 thr / 8 waves; tile M=256 (2 texts) x N=224, BK=64 (2 K=32 subtiles);
// A+B double-buffered in dynamic LDS; per BK-iter 4 phases of
// {ds_read subtile + 2 global_load_lds -> barrier -> setprio MFMA(14) -> barrier};
// counted vmcnt(4) (waves 6,7: 3) at phases 1 and 3 only.
#define ASLOT(cur,kh) (smem + ((cur)*2+(kh))*16384)
#define BSLOT(cur,kh) (smem + 65536 + ((cur)*2+(kh))*14336)

__global__ __launch_bounds__(512, 2)
void cmli_pair_kernel(const _Float16* __restrict__ txtH,
                      const _Float16* __restrict__ imgH,
                      const float* __restrict__ biasG,
                      const float* __restrict__ selG,
                      const int* __restrict__ cntG,
                      const float* __restrict__ scaleP,
                      float* __restrict__ out)
{
  extern __shared__ __align__(16) char smem[];
  unsigned* rowKeys = (unsigned*)(smem + LDS_RK);   // 256
  unsigned* colKeys = (unsigned*)(smem + LDS_CK);   // 2 x 256
  float*    parts   = (float*)(smem + LDS_PT);      // 16

  const int tid  = threadIdx.x;        // 0..511
  const int lane = tid & 63;
  const int w    = tid >> 6;           // 0..7
  const int wm   = w & 3;              // M quarter
  const int wn   = w >> 2;             // N half
  const int tx   = wm >> 1;            // text within block (0/1)
  const int gpar = wm & 1;             // m-tile parity class
  const int bxp  = blockIdx.x >> 6;    // text pair 0..31
  const int by   = blockIdx.x & 63;    // image

  const char* tA = (const char*)txtH + (size_t)(2*bxp) * (NK*A_KB);
  const char* tB = (const char*)imgH + (size_t)by * (NK*B_KB);
  const int cnt0 = cntG[2*bxp], cnt1 = cntG[2*bxp+1];
  const int mtcw = (((tx ? cnt1 : cnt0) + 15) >> 4);   // 4..8
  const bool act2 = (gpar + 4) < mtcw;
  const bool act3 = (gpar + 6) < mtcw;

  // --- staging tables (source pre-swizzled; linear LDS dest = swizzled layout) ---
  // A subtile: 256 rows x 64B = 1024 chunks of 16B; 2 per thread.
  int aSrc[2], aLds[2];
  #pragma unroll
  for (int i=0;i<2;i++){
    int c = tid + 512*i; int r = c>>2; int p = c&3; int g = p ^ ((r>>1)&3);
    int ttx = r>>7, tr = r&127;
    aSrc[i] = ttx*(NK*A_KB) + min(tr,126)*64 + g*16;
    aLds[i] = c*16;
  }
  // B subtile: 224 rows x 64B = 896 chunks; 2 per thread, second only for tid<384.
  const bool hasB1 = (tid < 384);      // wave-aligned (w<6)
  int bSrc[2], bLds[2];
  #pragma unroll
  for (int i=0;i<2;i++){
    int c = tid + 512*i; if (c > 895) c = 895;
    int r = c>>2; int p = c&3; int g = p ^ ((r>>1)&3);
    bSrc[i] = min(r,195)*64 + g*16;
    bLds[i] = c*16;
  }

  // fragment read offsets (swizzle-consistent)
  const int pgf   = (lane>>4) ^ ((lane>>1)&3);
  const int aBase = tx*8192 + gpar*1024 + (lane&15)*64 + pgf*16;   // + j*2048
  const int bOff  = (wn*112 + (lane&15))*64 + pgf*16;              // + n*1024

  f32x4 acc[4][7];
  #pragma unroll
  for (int j=0;j<4;j++)
    #pragma unroll
    for (int n=0;n<7;n++)
      acc[j][n] = (f32x4){0.f,0.f,0.f,0.f};

  if (tid < 256) rowKeys[tid] = 0u;
  colKeys[tid] = 0u;

  // --- prologue: stage iter-0 (k0 group then k1 group); drain k0, keep k1 ---
  {
    gload_lds16(tA + aSrc[0], ASLOT(0,0) + aLds[0]);
    gload_lds16(tA + aSrc[1], ASLOT(0,0) + aLds[1]);
    gload_lds16(tB + bSrc[0], BSLOT(0,0) + bLds[0]);
    if (hasB1) gload_lds16(tB + bSrc[1], BSLOT(0,0) + bLds[1]);
    gload_lds16(tA + A_KB + aSrc[0], ASLOT(0,1) + aLds[0]);
    gload_lds16(tA + A_KB + aSrc[1], ASLOT(0,1) + aLds[1]);
    gload_lds16(tB + B_KB + bSrc[0], BSLOT(0,1) + bLds[0]);
    if (hasB1) gload_lds16(tB + B_KB + bSrc[1], BSLOT(0,1) + bLds[1]);
    if (hasB1) asm volatile("s_waitcnt vmcnt(4)" ::: "memory");
    else       asm volatile("s_waitcnt vmcnt(3)" ::: "memory");
    __builtin_amdgcn_s_barrier();
  }

  #pragma unroll 2
  for (int t=0; t<NK2; t++){
    const int cur = t & 1, ncur = cur ^ 1;
    const char* A0c = ASLOT(cur,0);
    const char* A1c = ASLOT(cur,1);
    const char* B0c = BSLOT(cur,0);
    const char* B1c = BSLOT(cur,1);
    char* nA0 = ASLOT(ncur,0); char* nA1 = ASLOT(ncur,1);
    char* nB0 = BSLOT(ncur,0); char* nB1 = BSLOT(ncur,1);
    int ks0 = 2*t+2; if (ks0 > 23) ks0 = 23;   // t=11 stages dead data (clamped, in-bounds)
    int ks1 = 2*t+3; if (ks1 > 23) ks1 = 23;
    const char* pA0 = tA + (size_t)ks0*A_KB;
    const char* pA1 = tA + (size_t)ks1*A_KB;
    const char* pB0 = tB + (size_t)ks0*B_KB;
    const char* pB1 = tB + (size_t)ks1*B_KB;

    h8 bf[7]; h8 af0, af1, af2, af3;

    // ---------- phase 0 (kh=0, j=0,1 unconditional) ----------
    af0 = *(const h8*)(A0c + aBase);
    af1 = *(const h8*)(A0c + aBase + 2048);
    #pragma unroll
    for (int n=0;n<7;n++) bf[n] = *(const h8*)(B0c + bOff + n*1024);
    gload_lds16(pA0 + aSrc[0], nA0 + aLds[0]);
    gload_lds16(pA0 + aSrc[1], nA0 + aLds[1]);
    __builtin_amdgcn_s_barrier();
    __builtin_amdgcn_s_setprio(1);
    #pragma unroll
    for (int n=0;n<7;n++) acc[0][n] = __builtin_amdgcn_mfma_f32_16x16x32_f16(af0, bf[n], acc[0][n], 0,0,0);
    #pragma unroll
    for (int n=0;n<7;n++) acc[1][n] = __builtin_amdgcn_mfma_f32_16x16x32_f16(af1, bf[n], acc[1][n], 0,0,0);
    __builtin_amdgcn_s_setprio(0);
    __builtin_amdgcn_sched_barrier(0);
    __builtin_amdgcn_s_barrier();

    // ---------- phase 1 (kh=0, j=2,3 conditional; vmcnt) ----------
    if (act2) af2 = *(const h8*)(A0c + aBase + 4096);
    if (act3) af3 = *(const h8*)(A0c + aBase + 6144);
    gload_lds16(pB0 + bSrc[0], nB0 + bLds[0]);
    if (hasB1) gload_lds16(pB0 + bSrc[1], nB0 + bLds[1]);
    __builtin_amdgcn_s_barrier();
    __builtin_amdgcn_s_setprio(1);
    if (act2){
      #pragma unroll
      for (int n=0;n<7;n++) acc[2][n] = __builtin_amdgcn_mfma_f32_16x16x32_f16(af2, bf[n], acc[2][n], 0,0,0);
    }
    if (act3){
      #pragma unroll
      for (int n=0;n<7;n++) acc[3][n] = __builtin_amdgcn_mfma_f32_16x16x32_f16(af3, bf[n], acc[3][n], 0,0,0);
    }
    __builtin_amdgcn_s_setprio(0);
    __builtin_amdgcn_sched_barrier(0);
    if (hasB1) asm volatile("s_waitcnt vmcnt(4)" ::: "memory");
    else       asm volatile("s_waitcnt vmcnt(3)" ::: "memory");
    __builtin_amdgcn_s_barrier();

    // ---------- phase 2 (kh=1, j=0,1) ----------
    af0 = *(const h8*)(A1c + aBase);
    af1 = *(const h8*)(A1c + aBase + 2048);
    #pragma unroll
    for (int n=0;n<7;n++) bf[n] = *(const h8*)(B1c + bOff + n*1024);
    gload_lds16(pA1 + aSrc[0], nA1 + aLds[0]);
    gload_lds16(pA1 + aSrc[1], nA1 + aLds[1]);
    __builtin_amdgcn_s_barrier();
    __builtin_amdgcn_s_setprio(1);
    #pragma unroll
    for (int n=0;n<7;n++) acc[0][n] = __builtin_amdgcn_mfma_f32_16x16x32_f16(af0, bf[n], acc[0][n], 0,0,0);
    #pragma unroll
    for (int n=0;n<7;n++) acc[1][n] = __builtin_amdgcn_mfma_f32_16x16x32_f16(af1, bf[n], acc[1][n], 0,0,0);
    __builtin_amdgcn_s_setprio(0);
    __builtin_amdgcn_sched_barrier(0);
    __builtin_amdgcn_s_barrier();

    // ---------- phase 3 (kh=1, j=2,3; vmcnt) ----------
    if (act2) af2 = *(const h8*)(A1c + aBase + 4096);
    if (act3) af3 = *(const h8*)(A1c + aBase + 6144);
    gload_lds16(pB1 + bSrc[0], nB1 + bLds[0]);
    if (hasB1) gload_lds16(pB1 + bSrc[1], nB1 + bLds[1]);
    __builtin_amdgcn_s_barrier();
    __builtin_amdgcn_s_setprio(1);
    if (act2){
      #pragma unroll
      for (int n=0;n<7;n++) acc[2][n] = __builtin_amdgcn_mfma_f32_16x16x32_f16(af2, bf[n], acc[2][n], 0,0,0);
    }
    if (act3){
      #pragma unroll
      for (int n=0;n<7;n++) acc[3][n] = __builtin_amdgcn_mfma_f32_16x16x32_f16(af3, bf[n], acc[3][n], 0,0,0);
    }
    __builtin_amdgcn_s_setprio(0);
    __builtin_amdgcn_sched_barrier(0);
    if (hasB1) asm volatile("s_waitcnt vmcnt(4)" ::: "memory");
    else       asm volatile("s_waitcnt vmcnt(3)" ::: "memory");
    __builtin_amdgcn_s_barrier();
  }
  asm volatile("s_waitcnt vmcnt(0)" ::: "memory");

  // --- fused reductions ---
  const float scale = scaleP[0];
  #pragma unroll
  for (int j=0;j<4;j++){
    int g = gpar + 2*j;
    if (g < mtcw){
      #pragma unroll
      for (int n=0;n<7;n++) acc[j][n] *= scale;
    }
  }

  // rowmax (t2i); C/D map: row=(lane>>4)*4+q, col=lane&15
  #pragma unroll
  for (int j=0;j<4;j++){
    int g = gpar + 2*j;
    if (g < mtcw){
      f32x4 r = acc[j][0];
      #pragma unroll
      for (int n=1;n<7;n++){
        r.x = fmaxf(r.x, acc[j][n].x); r.y = fmaxf(r.y, acc[j][n].y);
        r.z = fmaxf(r.z, acc[j][n].z); r.w = fmaxf(r.w, acc[j][n].w);
      }
      #pragma unroll
      for (int s=1;s<16;s<<=1){
        r.x = fmaxf(r.x, __shfl_xor(r.x, s, 64));
        r.y = fmaxf(r.y, __shfl_xor(r.y, s, 64));
        r.z = fmaxf(r.z, __shfl_xor(r.z, s, 64));
        r.w = fmaxf(r.w, __shfl_xor(r.w, s, 64));
      }
      if ((lane & 15) == 0){
        int row = tx*128 + g*16 + (lane>>4)*4;
        atomicMax(&rowKeys[row+0], fkey(r.x));
        atomicMax(&rowKeys[row+1], fkey(r.y));
        atomicMax(&rowKeys[row+2], fkey(r.z));
        atomicMax(&rowKeys[row+3], fkey(r.w));
      }
    }
  }

  // colmax (i2t): per-text keys; bias = 0 valid / -3e38 masked
  #pragma unroll
  for (int n=0;n<7;n++){
    float c = -3.0e38f;
    #pragma unroll
    for (int j=0;j<4;j++){
      int g = gpar + 2*j;
      if (g < mtcw){
        fvec4 bv = *(const fvec4*)(biasG + (2*bxp+tx)*128 + g*16 + (lane>>4)*4);
        c = fmaxf(c, acc[j][n].x + bv.x);
        c = fmaxf(c, acc[j][n].y + bv.y);
        c = fmaxf(c, acc[j][n].z + bv.z);
        c = fmaxf(c, acc[j][n].w + bv.w);
      }
    }
    c = fmaxf(c, __shfl_xor(c, 16, 64));
    c = fmaxf(c, __shfl_xor(c, 32, 64));
    if (lane < 16){
      int col = wn*112 + n*16 + lane;
      atomicMax(&colKeys[tx*256 + col], fkey(c));
    }
  }
  __syncthreads();

  // finalize pair outputs (two texts per block)
  float v = 0.f;
  if (tid < 256){
    int ftx = tid >> 7;
    float s = selG[(2*bxp+ftx)*128 + (tid & 127)];
    v = (s > 0.5f) ? fdekey(rowKeys[tid]) : 0.f;
  }
  float u = 0.f;
  {
    int fcol = tid & 255;
    if (fcol < 196) u = fdekey(colKeys[tid]);
  }
  v = waveSum(v); u = waveSum(u);
  if (lane == 0){ parts[w] = v; parts[8+w] = u; }
  __syncthreads();
  if (tid == 0){
    #pragma unroll
    for (int ftx=0; ftx<2; ftx++){
      float numer = parts[2*ftx] + parts[2*ftx+1];
      float csum  = parts[8+4*ftx] + parts[8+4*ftx+1] + parts[8+4*ftx+2] + parts[8+4*ftx+3];
      int x = 2*bxp + ftx;
      float denom = fmaxf((float)(ftx ? cnt1 : cnt0), 1e-6f);
      out[1 + 4096 + x*64 + by] = numer / denom;       // t2i[x][y]
      out[1 + x*64 + by]        = csum * (1.f/196.f);  // i2t[x][y]
    }
  }
}

// ---------------------------------------------------------------------------
__global__ void loss_kernel(float* __restrict__ out){
  __shared__ float p[2];
  int w = threadIdx.x >> 6, lane = threadIdx.x & 63;
  const float* M = out + 1 + w*4096;
  const float* r = M + lane*64;
  float mx = -3.0e38f;
  for (int j=0;j<64;j++) mx = fmaxf(mx, r[j]);
  float se = 0.f;
  for (int j=0;j<64;j++) se += __expf(r[j]-mx);
  float nll = (mx + __logf(se)) - r[lane];
  float s = waveSum(nll);
  if (lane == 0) p[w] = s;
  __syncthreads();
  if (threadIdx.x == 0) out[0] = (p[0] + p[1]) * (0.5f/64.f);
}

// ---------------------------------------------------------------------------
extern "C" void kernel_launch(void* const* d_in, const int* in_sizes, int n_in,
                              void* d_out, int out_size, void* d_ws, size_t ws_size,
                              hipStream_t stream)
{
  const float* imgF   = (const float*)d_in[0];  // (64,197,768) f32
  const float* txtF   = (const float*)d_in[1];  // (64,128,768) f32
  const int*   pm     = (const int*)d_in[2];    // (64,128) i32
  const float* scaleP = (const float*)d_in[3];  // (1,) f32
  float* out = (float*)d_out;                   // [loss(1) | i2t(4096) | t2i(4096)]

  char* ws = (char*)d_ws;
  _Float16* txtH = (_Float16*)ws;                        // 12,484,608 B
  _Float16* imgH = (_Float16*)(ws + 12484608);           // 19,267,584 B
  float* bias = (float*)(ws + 31752192);                 // 32 KB
  float* sel  = (float*)(ws + 31784960);                 // 32 KB
  int*   cnt  = (int*)(ws + 31817728);                   // 256 B

  static int lds_set = 0;
  (void)lds_set;
  hipFuncSetAttribute((const void*)cmli_pair_kernel,
                      hipFuncAttributeMaxDynamicSharedMemorySize, LDS_TOT);

  hipLaunchKernelGGL(mask_kernel,    dim3(BB),      dim3(64),  0, stream, pm, bias, sel, cnt);
  hipLaunchKernelGGL(cvt_txt_kernel, dim3(TM, BB),  dim3(192), 0, stream, txtF, txtH);
  hipLaunchKernelGGL(cvt_img_kernel, dim3(IM, BB),  dim3(192), 0, stream, imgF, imgH);
  hipLaunchKernelGGL(cmli_pair_kernel, dim3(32*BB), dim3(512), LDS_TOT, stream,
                     txtH, imgH, bias, sel, cnt, scaleP, out);
  hipLaunchKernelGGL(loss_kernel,    dim3(1),       dim3(128), 0, stream, out);
}